// Round 2
// baseline (558.608 us; speedup 1.0000x reference)
//
#include <hip/hip_runtime.h>
#include <hip/hip_bf16.h>

// Problem constants
#define NB   8      // batch
#define NH   252    // height
#define NW   192    // width
#define NC   64     // channels
#define HHD  84     // hh = H/3
#define WWD  64     // ww = W/3
#define NE   192    // embed
#define NO   486    // K^4 * HEADS
#define NWIN (NB*HHD*WWD)   // 43008 windows
#define SCALE_F 0.17677669529663687f  // 32^-0.5

typedef __bf16 bf16x8 __attribute__((ext_vector_type(8)));
typedef __bf16 bf16x4 __attribute__((ext_vector_type(4)));
typedef float floatx4 __attribute__((ext_vector_type(4)));

// Precomputed weights (bf16, written by kt_prep each call):
//   g_WT[e][h*64+c]  = sum_d v_w[c][h*32+d] * out_w[h*32+d][e]   (fused V+output proj)
//   g_awT[n][c]      = attn_w[c][n]                               (logit weights, transposed)
__device__ __attribute__((aligned(16))) __hip_bfloat16 g_WT[NE * 384];
__device__ __attribute__((aligned(16))) __hip_bfloat16 g_awT[NO * 64];

__device__ __forceinline__ bf16x8 bf16x8_zero() {
    bf16x8 z;
    #pragma unroll
    for (int j = 0; j < 8; ++j) z[j] = (__bf16)0.f;
    return z;
}

// Per-M-tile K-slice offset for the stride-10 block-diagonal layout.
// Tile t (rows 16t..16t+15, row R = win*10+p) has all nonzero cols within
// [off(t), off(t)+31]:  off = clamp(16t-8, 0, 48) -> {0,8,24,40,48}.
__device__ __forceinline__ int koff(int t) {
    int v = 16 * t - 8;
    v = v < 0 ? 0 : v;
    return v > 48 ? 48 : v;
}

// ---------------------------------------------------------------------------
// Kernel T: build g_WT (fp32 accumulate of v_w @ out_w per head, then bf16)
// and g_awT (transpose+cvt of attn_w).
// ---------------------------------------------------------------------------
__global__ __launch_bounds__(256) void kt_prep(
    const float* __restrict__ vw, const float* __restrict__ ow,
    const float* __restrict__ aw)
{
    int t = blockIdx.x * 256 + threadIdx.x;
    if (t < NE * 384) {
        int e  = t / 384;
        int hc = t - e * 384;        // h*64 + c
        int h  = hc >> 6;
        int c  = hc & 63;
        float s = 0.f;
        #pragma unroll
        for (int d = 0; d < 32; ++d)
            s = fmaf(vw[c * NE + h * 32 + d], ow[(h * 32 + d) * NE + e], s);
        g_WT[e * 384 + hc] = __float2bfloat16(s);
    } else {
        int tt = t - NE * 384;
        if (tt < NO * 64) {
            int n = tt >> 6;
            int c = tt & 63;
            g_awT[tt] = __float2bfloat16(aw[c * NO + n]);
        }
    }
}

// ---------------------------------------------------------------------------
// Kernel A (fused, stride-10 layout): per block = 8 windows = 72 pixels,
// stored as 80 slots (10 per window, slot 9 = zero pad).
//   ph0:  x -> xwT bf16 [c][p10] (b64-packed transposed writes); zero attnA
//   ph0.5: pooled = mean of 9 pixels -> pooledB (aliased into Ph)
//   ph1:  logits MFMA (A=pooled, B=g_awT), scatter straight into attnA
//         block-diag slots: row R=win*10+p, col win*10+q-off(t)
//   ph2:  softmax in-place on attnA (9 contiguous cols per group)
//   per head h (6x, fully unrolled):
//     B: P_h = attn_h @ x -- 5 MFMA (one per M-tile, single K-slice each)
//     C: accF += P_h @ W_h (2ks x 5mt x 3nt = 30 MFMA, W from g_WT/L2)
//   epilogue: out = accF + out_b, skip pad rows (p==9)
// LDS: 11264 (xwT) + 30720 (attnA) + 11520 (Ph) = 53504 -> 3 blocks/CU.
// ---------------------------------------------------------------------------
__global__ __launch_bounds__(256, 3) void ka_fused(
    const float* __restrict__ x,
    const float* __restrict__ attn_b,
    const float* __restrict__ out_b,
    float* __restrict__ out)
{
    __shared__ __attribute__((aligned(16))) __bf16 xwT[64 * 88];        // [c][p10] 11264 B
    __shared__ __attribute__((aligned(16))) __bf16 attnA[6 * 5 * 16 * 32]; // 30720 B
    __shared__ __attribute__((aligned(16))) __bf16 Ph[80 * 72];         // 11520 B

    __bf16* pooledB = Ph;   // [win][c] 8x64; frag overrun rows 8..15 read Ph garbage (discarded)

    const int tid  = threadIdx.x;
    const int lane = tid & 63;
    const int wv   = tid >> 6;
    const int m16  = lane & 15;
    const int quad = lane >> 4;
    const int wbase = blockIdx.x * 8;

    // All 8 windows of a block share (b, i); j = jB + win (5376 % 8 == 0).
    const int bB   = wbase / 5376;
    const int remB = wbase - bB * 5376;
    const int iB   = remB >> 6;
    const int jB   = remB & 63;
    const int xbase = ((bB * NH + iB * 3) * NW + jB * 3) * NC;

    // --- Phase 0: load x (coalesced over c) -> xwT, b64-packed; pads -> 0 ---
    #pragma unroll
    for (int i = 0; i < 5; ++i) {
        int b4 = i * 4 + wv;                 // 4-pixel block 0..19
        bf16x4 pk;
        #pragma unroll
        for (int s = 0; s < 4; ++s) {
            int p10 = b4 * 4 + s;
            int w = p10 / 10;
            int q = p10 - w * 10;
            float xv = 0.f;
            if (q < 9) {                     // wave-uniform branch
                int pr = q / 3;
                int pc = q - pr * 3;
                xv = x[xbase + (pr * NW + w * 3 + pc) * NC + lane];
            }
            pk[s] = (__bf16)xv;
        }
        *(bf16x4*)(&xwT[lane * 88 + b4 * 4]) = pk;
    }
    // zero attnA (block-diag pad; scatter fills only valid slots)
    #pragma unroll
    for (int i = 0; i < 8; ++i) {
        int ch = i * 256 + tid;              // 16B chunks, 30720/16 = 1920
        if (ch < 1920) *(uint4*)(&attnA[ch * 8]) = make_uint4(0u, 0u, 0u, 0u);
    }
    __syncthreads();

    // --- Phase 0.5: pooled = mean over 9 pixels ---
    #pragma unroll
    for (int i = 0; i < 2; ++i) {
        int win = i * 4 + wv;
        float s = 0.f;
        #pragma unroll
        for (int q = 0; q < 9; ++q) s += (float)xwT[lane * 88 + win * 10 + q];
        pooledB[win * 64 + lane] = (__bf16)(s * (1.f / 9.f));
    }
    __syncthreads();

    // --- Phase 1: logits via MFMA, scatter directly into attnA block-diag ---
    {
        bf16x8 afragP[2];
        #pragma unroll
        for (int ks = 0; ks < 2; ++ks)
            afragP[ks] = *(const bf16x8*)(&pooledB[m16 * 64 + ks * 32 + quad * 8]);
        const __bf16* Aw = (const __bf16*)g_awT;
        #pragma unroll
        for (int i = 0; i < 8; ++i) {
            int tile = wv * 8 + i;           // 31 tiles of 16 cover N=486
            int n = tile * 16 + m16;
            bool nvalid = (tile < 31) && (n < NO);
            bf16x8 b0 = nvalid ? *(const bf16x8*)(Aw + n * 64 + quad * 8)      : bf16x8_zero();
            bf16x8 b1 = nvalid ? *(const bf16x8*)(Aw + n * 64 + 32 + quad * 8) : bf16x8_zero();
            floatx4 acc;
            acc[0] = 0.f; acc[1] = 0.f; acc[2] = 0.f; acc[3] = 0.f;
            acc = __builtin_amdgcn_mfma_f32_16x16x32_bf16(afragP[0], b0, acc, 0, 0, 0);
            acc = __builtin_amdgcn_mfma_f32_16x16x32_bf16(afragP[1], b1, acc, 0, 0, 0);
            if (nvalid && quad < 2) {        // D rows 0..7 = windows
                float bn = attn_b[n];
                int h   = n / 81;
                int r81 = n - h * 81;
                int p   = r81 / 9;
                int q   = r81 - p * 9;
                #pragma unroll
                for (int r = 0; r < 4; ++r) {
                    int win = quad * 4 + r;
                    int R   = win * 10 + p;
                    int t   = R >> 4;
                    int rl  = R & 15;
                    int col = win * 10 + q - koff(t);
                    attnA[((h * 5 + t) * 16 + rl) * 32 + col] =
                        (__bf16)((acc[r] + bn) * SCALE_F);
                }
            }
        }
    }
    __syncthreads();

    // --- Phase 2: softmax in-place (groups of 9 contiguous cols) ---
    #pragma unroll
    for (int it = 0; it < 2; ++it) {
        int g = it * 256 + tid;
        if (g < 432) {                       // 8 win * 6 h * 9 p
            int win  = g / 54;
            int rest = g - win * 54;
            int h = rest / 9;
            int p = rest - h * 9;
            int R  = win * 10 + p;
            int t  = R >> 4;
            int rl = R & 15;
            int cb = win * 10 - koff(t);
            __bf16* a = &attnA[((h * 5 + t) * 16 + rl) * 32 + cb];
            float v[9];
            float m = -1e30f;
            #pragma unroll
            for (int q = 0; q < 9; ++q) { v[q] = (float)a[q]; m = fmaxf(m, v[q]); }
            float ssum = 0.f;
            #pragma unroll
            for (int q = 0; q < 9; ++q) { v[q] = __expf(v[q] - m); ssum += v[q]; }
            float inv = 1.f / ssum;
            #pragma unroll
            for (int q = 0; q < 9; ++q) a[q] = (__bf16)(v[q] * inv);
        }
    }
    __syncthreads();

    // --- Head loop ---
    bf16x8 bfragX[5];                        // B-frags of x, one per M-tile's K-slice
    #pragma unroll
    for (int t = 0; t < 5; ++t)
        bfragX[t] = *(const bf16x8*)(&xwT[(wv * 16 + m16) * 88 + koff(t) + quad * 8]);

    float bias[3];
    #pragma unroll
    for (int nt = 0; nt < 3; ++nt) bias[nt] = out_b[wv * 48 + nt * 16 + m16];

    floatx4 accF[5][3];
    #pragma unroll
    for (int mt = 0; mt < 5; ++mt)
        #pragma unroll
        for (int nt = 0; nt < 3; ++nt) {
            accF[mt][nt][0] = 0.f; accF[mt][nt][1] = 0.f;
            accF[mt][nt][2] = 0.f; accF[mt][nt][3] = 0.f;
        }

    const __bf16* Wt = (const __bf16*)g_WT;

    #pragma unroll
    for (int h = 0; h < 6; ++h) {
        // B: P_h = attn_h @ x   (5 MFMA: one K-slice per M-tile)
        {
            floatx4 accP[5];
            #pragma unroll
            for (int mt = 0; mt < 5; ++mt) {
                accP[mt][0] = 0.f; accP[mt][1] = 0.f;
                accP[mt][2] = 0.f; accP[mt][3] = 0.f;
                bf16x8 af = *(const bf16x8*)(&attnA[((h * 5 + mt) * 16 + m16) * 32 + quad * 8]);
                accP[mt] = __builtin_amdgcn_mfma_f32_16x16x32_bf16(af, bfragX[mt], accP[mt], 0, 0, 0);
            }
            #pragma unroll
            for (int mt = 0; mt < 5; ++mt)
                #pragma unroll
                for (int r = 0; r < 4; ++r)
                    Ph[(mt * 16 + quad * 4 + r) * 72 + wv * 16 + m16] = (__bf16)accP[mt][r];
        }
        __syncthreads();

        // C: accF += P_h @ W_h   (M=80, N=192 split 48/wave, K=64)
        #pragma unroll
        for (int ks = 0; ks < 2; ++ks) {
            bf16x8 bw[3];
            #pragma unroll
            for (int nt = 0; nt < 3; ++nt)
                bw[nt] = *(const bf16x8*)(Wt + (wv * 48 + nt * 16 + m16) * 384 + h * 64 + ks * 32 + quad * 8);
            #pragma unroll
            for (int mt = 0; mt < 5; ++mt) {
                bf16x8 af = *(const bf16x8*)(&Ph[(mt * 16 + m16) * 72 + ks * 32 + quad * 8]);
                #pragma unroll
                for (int nt = 0; nt < 3; ++nt)
                    accF[mt][nt] = __builtin_amdgcn_mfma_f32_16x16x32_bf16(af, bw[nt], accF[mt][nt], 0, 0, 0);
            }
        }
        if (h < 5) __syncthreads();          // Ph reuse guard for next head's B
    }

    // --- Epilogue: fp32 scatter stores, skip pad rows (p == 9) ---
    const int obase = ((bB * NH + iB * 3) * NW + jB * 3) * NE;
    #pragma unroll
    for (int mt = 0; mt < 5; ++mt)
        #pragma unroll
        for (int r = 0; r < 4; ++r) {
            int row = mt * 16 + quad * 4 + r;
            int win = row / 10;
            int p   = row - win * 10;
            if (p < 9) {
                int pr = p / 3;
                int pc = p - pr * 3;
                int base = obase + (pr * NW + win * 3 + pc) * NE;
                #pragma unroll
                for (int nt = 0; nt < 3; ++nt)
                    out[base + wv * 48 + nt * 16 + m16] = accF[mt][nt][r] + bias[nt];
            }
        }
}

extern "C" void kernel_launch(void* const* d_in, const int* in_sizes, int n_in,
                              void* d_out, int out_size, void* d_ws, size_t ws_size,
                              hipStream_t stream)
{
    const float* x      = (const float*)d_in[0];
    const float* v_w    = (const float*)d_in[1];
    const float* attn_w = (const float*)d_in[2];
    const float* attn_b = (const float*)d_in[3];
    const float* out_w  = (const float*)d_in[4];
    const float* out_b  = (const float*)d_in[5];
    float* out = (float*)d_out;
    (void)d_ws; (void)ws_size; (void)in_sizes; (void)n_in; (void)out_size;

    // 410 blocks cover NE*384 + NO*64 = 104832 prep elements
    hipLaunchKernelGGL(kt_prep, dim3(410), dim3(256), 0, stream, v_w, out_w, attn_w);
    hipLaunchKernelGGL(ka_fused, dim3(NWIN / 8), dim3(256), 0, stream,
                       x, attn_b, out_b, out);
}

// Round 3
// 551.285 us; speedup vs baseline: 1.0133x; 1.0133x over previous
//
#include <hip/hip_runtime.h>
#include <hip/hip_bf16.h>

// Problem constants
#define NB   8      // batch
#define NH   252    // height
#define NW   192    // width
#define NC   64     // channels
#define NE   192    // embed
#define NO   486    // K^4 * HEADS
#define NWIN (NB*84*64)     // 43008 windows
#define SCALE_F 0.17677669529663687f  // 32^-0.5

typedef __bf16 bf16x8 __attribute__((ext_vector_type(8)));
typedef __bf16 bf16x4 __attribute__((ext_vector_type(4)));
typedef float floatx4 __attribute__((ext_vector_type(4)));

// Precomputed weights (bf16, written by kt_prep each call):
//   g_WT[e][h*64+c]  = sum_d v_w[c][h*32+d] * out_w[h*32+d][e]   (fused V+output proj)
//   g_awT[n][c]      = attn_w[c][n]                               (logit weights, transposed)
__device__ __attribute__((aligned(16))) __hip_bfloat16 g_WT[NE * 384];
__device__ __attribute__((aligned(16))) __hip_bfloat16 g_awT[NO * 64];

__device__ __forceinline__ bf16x8 bf16x8_zero() {
    bf16x8 z;
    #pragma unroll
    for (int j = 0; j < 8; ++j) z[j] = (__bf16)0.f;
    return z;
}

// Per-M-tile K-slice offset for the stride-10 block-diagonal layout.
// Tile t (rows 16t..16t+15, row R = win*10+p) has nonzero cols within
// [off(t), off(t)+31]:  off = clamp(16t-8, 0, 48) -> {0,8,24,40,48}.
// All values are multiples of 8 (one swizzle block).
__device__ __forceinline__ int koff(int t) {
    int v = 16 * t - 8;
    v = v < 0 ? 0 : v;
    return v > 48 ? 48 : v;
}

// XOR-16 swizzled index into xwT[64][128]: row c (256 B = 16 blocks of 16 B),
// pixel p lives in block p>>3 ^ (c&15), halfword (p&7).
__device__ __forceinline__ int xw_idx(int c, int p) {
    return c * 128 + ((((p) >> 3) ^ (c & 15)) << 3) + ((p) & 7);
}

// 8B-aligned bf16x8 load as two b64s (for 72/136-byte row strides).
__device__ __forceinline__ bf16x8 ld_b64x2(const __bf16* p) {
    union { bf16x4 h[2]; bf16x8 v; } u;
    u.h[0] = *(const bf16x4*)p;
    u.h[1] = *(const bf16x4*)(p + 4);
    return u.v;
}

// ---------------------------------------------------------------------------
// Kernel T: build g_WT (fp32 accumulate of v_w @ out_w per head, then bf16)
// and g_awT (transpose+cvt of attn_w).
// ---------------------------------------------------------------------------
__global__ __launch_bounds__(256) void kt_prep(
    const float* __restrict__ vw, const float* __restrict__ ow,
    const float* __restrict__ aw)
{
    int t = blockIdx.x * 256 + threadIdx.x;
    if (t < NE * 384) {
        int e  = t / 384;
        int hc = t - e * 384;        // h*64 + c
        int h  = hc >> 6;
        int c  = hc & 63;
        float s = 0.f;
        #pragma unroll
        for (int d = 0; d < 32; ++d)
            s = fmaf(vw[c * NE + h * 32 + d], ow[(h * 32 + d) * NE + e], s);
        g_WT[e * 384 + hc] = __float2bfloat16(s);
    } else {
        int tt = t - NE * 384;
        if (tt < NO * 64) {
            int n = tt >> 6;
            int c = tt & 63;
            g_awT[tt] = __float2bfloat16(aw[c * NO + n]);
        }
    }
}

// ---------------------------------------------------------------------------
// Kernel A (fused): per block = 8 windows = 72 pixels in 80 stride-10 slots.
// Layout design targets <=2-way LDS bank conflicts on every access:
//   xwT  [64][128] bf16, XOR-16 swizzled   (16384 B)  x^T, b64 writes / blk reads
//   attnS[8][486]  bf16 (972 B = odd banks) (7776 B)  logits+softmax, compact
//   attnBD[5][16][36] bf16 (72 B rows)      (5760 B)  per-head block-diag
//   PhS  [80][68]  bf16 (136 B rows)       (10880 B)  P_h; pooled aliases head
// Total 40800 -> rounds to 40960 B -> 4 blocks/CU (16 waves, occupancy 50%).
// Head pipeline: scatter(h+1) overlaps C(h); 2 barriers per head.
// Phase B computes P^T (A = x^T frags, B = attn rows) so each lane emits 4
// consecutive channels of one pixel -> packed b64 Ph writes.
// ---------------------------------------------------------------------------
__global__ __launch_bounds__(256, 4) void ka_fused(
    const float* __restrict__ x,
    const float* __restrict__ attn_b,
    const float* __restrict__ out_b,
    float* __restrict__ out)
{
    __shared__ __attribute__((aligned(16))) __bf16 xwT[64 * 128];
    __shared__ __attribute__((aligned(16))) __bf16 attnS[8 * 486];
    __shared__ __attribute__((aligned(16))) __bf16 attnBD[5 * 16 * 36];
    __shared__ __attribute__((aligned(16))) __bf16 PhS[80 * 68];

    __bf16* pooled = PhS;   // [win][c] stride 72; dead before PhS first written

    const int tid  = threadIdx.x;
    const int lane = tid & 63;
    const int wv   = tid >> 6;
    const int m16  = lane & 15;
    const int quad = lane >> 4;
    const int wbase = blockIdx.x * 8;

    // All 8 windows of a block share (b, i); j = jB + win (5376 % 8 == 0).
    const int bB   = wbase / 5376;
    const int remB = wbase - bB * 5376;
    const int iB   = remB >> 6;
    const int jB   = remB & 63;
    const int xbase = ((bB * NH + iB * 3) * NW + jB * 3) * NC;

    // --- Phase 0: load x (coalesced over c=lane) -> swizzled xwT; pads -> 0 ---
    #pragma unroll
    for (int i = 0; i < 5; ++i) {
        int b4 = i * 4 + wv;                 // 4-pixel group 0..19
        bf16x4 pk;
        #pragma unroll
        for (int s = 0; s < 4; ++s) {
            int p10 = b4 * 4 + s;
            int w = p10 / 10;
            int q = p10 - w * 10;
            float xv = 0.f;
            if (q < 9) {                     // wave-uniform branch
                int pr = q / 3;
                int pc = q - pr * 3;
                xv = x[xbase + (pr * NW + w * 3 + pc) * NC + lane];
            }
            pk[s] = (__bf16)xv;
        }
        // blk = b4>>1, half = b4&1 (p10 = b4*4 is 4-aligned within 8-blk)
        *(bf16x4*)(&xwT[lane * 128 + (((b4 >> 1) ^ (lane & 15)) << 3) + (b4 & 1) * 4]) = pk;
    }
    // zero attnBD once (off-diagonal stays zero; scatter fills valid slots)
    #pragma unroll
    for (int i = 0; i < 2; ++i) {
        int ch = i * 256 + tid;              // 16B chunks: 5760/16 = 360
        if (ch < 360) *(uint4*)(&attnBD[ch * 8]) = make_uint4(0u, 0u, 0u, 0u);
    }
    __syncthreads();

    // --- Phase 0.5: pooled = mean over 9 pixels (swizzled scalar reads) ---
    #pragma unroll
    for (int i = 0; i < 2; ++i) {
        int win = i * 4 + wv;
        float s = 0.f;
        #pragma unroll
        for (int q = 0; q < 9; ++q) s += (float)xwT[xw_idx(lane, win * 10 + q)];
        pooled[win * 72 + lane] = (__bf16)(s * (1.f / 9.f));
    }
    __syncthreads();

    // --- Phase 1: logits via MFMA -> attnS ---
    {
        bf16x8 afragP[2];
        #pragma unroll
        for (int ks = 0; ks < 2; ++ks)      // rows 8..15 read garbage, discarded
            afragP[ks] = *(const bf16x8*)(&pooled[m16 * 72 + ks * 32 + quad * 8]);
        const __bf16* Aw = (const __bf16*)g_awT;
        #pragma unroll
        for (int i = 0; i < 8; ++i) {
            int tile = wv * 8 + i;           // 31 tiles of 16 cover N=486
            int n = tile * 16 + m16;
            bool nvalid = (tile < 31) && (n < NO);
            bf16x8 b0 = nvalid ? *(const bf16x8*)(Aw + n * 64 + quad * 8)      : bf16x8_zero();
            bf16x8 b1 = nvalid ? *(const bf16x8*)(Aw + n * 64 + 32 + quad * 8) : bf16x8_zero();
            floatx4 acc;
            acc[0] = 0.f; acc[1] = 0.f; acc[2] = 0.f; acc[3] = 0.f;
            acc = __builtin_amdgcn_mfma_f32_16x16x32_bf16(afragP[0], b0, acc, 0, 0, 0);
            acc = __builtin_amdgcn_mfma_f32_16x16x32_bf16(afragP[1], b1, acc, 0, 0, 0);
            if (nvalid && quad < 2) {        // D rows 0..7 = windows
                float bn = attn_b[n];
                #pragma unroll
                for (int r = 0; r < 4; ++r)
                    attnS[(quad * 4 + r) * 486 + n] = (__bf16)((acc[r] + bn) * SCALE_F);
            }
        }
    }
    __syncthreads();

    // --- Phase 2: softmax over groups of 9 (contiguous in attnS) ---
    #pragma unroll
    for (int it = 0; it < 2; ++it) {
        int t = it * 256 + tid;
        if (t < 432) {                       // 8 win * 54 groups
            int win = t / 54;
            int g = t - win * 54;
            __bf16* a = &attnS[win * 486 + g * 9];
            float v[9];
            float m = -1e30f;
            #pragma unroll
            for (int q = 0; q < 9; ++q) { v[q] = (float)a[q]; m = fmaxf(m, v[q]); }
            float ssum = 0.f;
            #pragma unroll
            for (int q = 0; q < 9; ++q) { v[q] = __expf(v[q] - m); ssum += v[q]; }
            float inv = 1.f / ssum;
            #pragma unroll
            for (int q = 0; q < 9; ++q) a[q] = (__bf16)(v[q] * inv);
        }
    }
    __syncthreads();

    // --- Prep for head loop ---
    // A-frags of x^T (swapped phase B): lane m16 = channel row c = wv*16+m16,
    // regs = pixels koff(nt)+quad*8..+7 -> exactly one swizzled 16B block.
    bf16x8 bfragX[5];
    #pragma unroll
    for (int nt = 0; nt < 5; ++nt) {
        int c  = wv * 16 + m16;
        int p0 = koff(nt) + quad * 8;
        bfragX[nt] = *(const bf16x8*)(&xwT[c * 128 + (((p0 >> 3) ^ (c & 15)) << 3)]);
    }

    float bias[3];
    #pragma unroll
    for (int nt = 0; nt < 3; ++nt) bias[nt] = out_b[wv * 48 + nt * 16 + m16];

    floatx4 accF[5][3];
    #pragma unroll
    for (int mt = 0; mt < 5; ++mt)
        #pragma unroll
        for (int nt = 0; nt < 3; ++nt) {
            accF[mt][nt][0] = 0.f; accF[mt][nt][1] = 0.f;
            accF[mt][nt][2] = 0.f; accF[mt][nt][3] = 0.f;
        }

    // scatter head 0 into attnBD
    #pragma unroll
    for (int it = 0; it < 3; ++it) {
        int t = it * 256 + tid;
        if (t < 648) {
            int win = t / 81;
            int r81 = t - win * 81;
            int p = r81 / 9;
            int q = r81 - p * 9;
            int R  = win * 10 + p;
            int tt = R >> 4;
            int rl = R & 15;
            attnBD[(tt * 16 + rl) * 36 + win * 10 + q - koff(tt)] = attnS[win * 486 + r81];
        }
    }
    __syncthreads();

    const __bf16* Wt = (const __bf16*)g_WT;

    // --- Head loop: 2 barriers per head; scatter(h+1) overlaps C(h) ---
    #pragma unroll
    for (int h = 0; h < 6; ++h) {
        // B(h): P^T = x^T @ attn^T.  Per wave: M-strip c = wv*16..+15, all 5
        // pixel N-tiles, one 32-wide K-slice each (block-diag) = 5 MFMA.
        {
            floatx4 accP[5];
            #pragma unroll
            for (int nt = 0; nt < 5; ++nt) {
                accP[nt][0] = 0.f; accP[nt][1] = 0.f;
                accP[nt][2] = 0.f; accP[nt][3] = 0.f;
                bf16x8 bfrag = ld_b64x2(&attnBD[(nt * 16 + m16) * 36 + quad * 8]);
                accP[nt] = __builtin_amdgcn_mfma_f32_16x16x32_bf16(bfragX[nt], bfrag, accP[nt], 0, 0, 0);
            }
            // D: col=m16 -> pixel nt*16+m16; rows quad*4+r -> c = wv*16+quad*4+r
            // 4 consecutive channels per lane -> packed b64 write.
            #pragma unroll
            for (int nt = 0; nt < 5; ++nt) {
                bf16x4 pk;
                #pragma unroll
                for (int r = 0; r < 4; ++r) pk[r] = (__bf16)accP[nt][r];
                *(bf16x4*)(&PhS[(nt * 16 + m16) * 68 + wv * 16 + quad * 4]) = pk;
            }
        }
        __syncthreads();

        // C(h): accF += P_h @ W_h   (M=80, N=192 split 48/wave, K=64)
        #pragma unroll
        for (int ks = 0; ks < 2; ++ks) {
            bf16x8 bw[3];
            #pragma unroll
            for (int nt = 0; nt < 3; ++nt)
                bw[nt] = *(const bf16x8*)(Wt + (wv * 48 + nt * 16 + m16) * 384 + h * 64 + ks * 32 + quad * 8);
            #pragma unroll
            for (int mt = 0; mt < 5; ++mt) {
                bf16x8 af = ld_b64x2(&PhS[(mt * 16 + m16) * 68 + ks * 32 + quad * 8]);
                #pragma unroll
                for (int nt = 0; nt < 3; ++nt)
                    accF[mt][nt] = __builtin_amdgcn_mfma_f32_16x16x32_bf16(af, bw[nt], accF[mt][nt], 0, 0, 0);
            }
        }
        // scatter(h+1) overlapped with C(h): BD reads finished before prev sync
        if (h < 5) {
            #pragma unroll
            for (int it = 0; it < 3; ++it) {
                int t = it * 256 + tid;
                if (t < 648) {
                    int win = t / 81;
                    int r81 = t - win * 81;
                    int p = r81 / 9;
                    int q = r81 - p * 9;
                    int R  = win * 10 + p;
                    int tt = R >> 4;
                    int rl = R & 15;
                    attnBD[(tt * 16 + rl) * 36 + win * 10 + q - koff(tt)] =
                        attnS[win * 486 + (h + 1) * 81 + r81];
                }
            }
            __syncthreads();
        }
    }

    // --- Epilogue: fp32 scatter stores, skip pad rows (p == 9) ---
    const int obase = ((bB * NH + iB * 3) * NW + jB * 3) * NE;
    #pragma unroll
    for (int mt = 0; mt < 5; ++mt)
        #pragma unroll
        for (int r = 0; r < 4; ++r) {
            int row = mt * 16 + quad * 4 + r;
            int win = row / 10;
            int p   = row - win * 10;
            if (p < 9) {
                int pr = p / 3;
                int pc = p - pr * 3;
                int base = obase + (pr * NW + win * 3 + pc) * NE;
                #pragma unroll
                for (int nt = 0; nt < 3; ++nt)
                    out[base + wv * 48 + nt * 16 + m16] = accF[mt][nt][r] + bias[nt];
            }
        }
}

extern "C" void kernel_launch(void* const* d_in, const int* in_sizes, int n_in,
                              void* d_out, int out_size, void* d_ws, size_t ws_size,
                              hipStream_t stream)
{
    const float* x      = (const float*)d_in[0];
    const float* v_w    = (const float*)d_in[1];
    const float* attn_w = (const float*)d_in[2];
    const float* attn_b = (const float*)d_in[3];
    const float* out_w  = (const float*)d_in[4];
    const float* out_b  = (const float*)d_in[5];
    float* out = (float*)d_out;
    (void)d_ws; (void)ws_size; (void)in_sizes; (void)n_in; (void)out_size;

    // 410 blocks cover NE*384 + NO*64 = 104832 prep elements
    hipLaunchKernelGGL(kt_prep, dim3(410), dim3(256), 0, stream, v_w, out_w, attn_w);
    hipLaunchKernelGGL(ka_fused, dim3(NWIN / 8), dim3(256), 0, stream,
                       x, attn_b, out_b, out);
}